// Round 13
// baseline (188.819 us; speedup 1.0000x reference)
//
#include <hip/hip_runtime.h>
#include <math.h>

#define R_NODES 1152
#define DIGITS 10
#define OUT_CH 16
#define IN_CH 8
#define BATCH 256
#define COLS 160            // DIGITS*OUT_CH
#define W_PER_R 1280        // DIGITS*OUT_CH*IN_CH
#define NSPLIT 192          // K-split: 6 r-rows per block
#define RPS 6               // rows per split
#define YBLK 8              // k_a batch blocks (32 b each)
#define UPAD 51             // u-LDS batch stride: (4*51)%32=12 -> <=2-way alias (free)
#define AB_STRIDE (YBLK * R_NODES * DIGITS)   // 92160 floats per ab iteration-buffer

// ---------- s partials: o-lane layout, W global->regs (L1), u via LDS ----------
// grid (192, 4). 256 thr = 16 o-lanes x 16 bs; thread owns batches bs*4+jj
// (jj=0..3, CONSECUTIVE) and cols d*16+o (d=0..9).
// NEW (r13): part and s are TRANSPOSED to [col][batch]. Store is one float4
// {acc[0..3][d]} at col*256 + b: 32 cache lines per store wave-instr vs ~960
// for the old strided scalar stores (the one cost every k_s variant shared).
__global__ __launch_bounds__(256, 4) void k_s(
    const float* __restrict__ u,      // [B][R][8]
    const float* __restrict__ W,      // [R][10][16][8]
    const float* __restrict__ ab,     // [nbuf][YBLK][R][10] agreement partials
    float* __restrict__ part,         // [NSPLIT][160][256]  (transposed!)
    float* __restrict__ sq,
    int nbuf)
{
    __shared__ float ut[64 * UPAD];     // 13,056 B
    __shared__ float cs[RPS * DIGITS];  // c for this block's 6 rows

    const int split = blockIdx.x;
    const int b0 = blockIdx.y * 64;
    const int t = threadIdx.x;
    const int o = t & 15;
    const int bs = t >> 4;
    const int r0 = split * RPS;

    if (split == 0 && blockIdx.y == 0 && t == 0) *sq = 0.f;

    // ---- 1. stage u-tile (3 float4/thread, coalesced 192B runs per batch)
    float4 ur[3]; int ub_[3], uq_[3];
#pragma unroll
    for (int p = 0; p < 3; ++p) {
        int idx = t + p * 256;            // 0..767
        int b = idx / 12, q = idx - b * 12;   // batch 0..63, float4 0..11
        ub_[p] = b; uq_[p] = q;
        ur[p] = ((const float4*)(u + (size_t)(b0 + b) * (R_NODES * IN_CH)
                                   + (size_t)r0 * IN_CH))[q];
    }
#pragma unroll
    for (int p = 0; p < 3; ++p)
        *(float4*)&ut[ub_[p] * UPAD + uq_[p] * 4] = ur[p];

    // ---- 2. c logits for rows r0..r0+5 (0 if nbuf==0 -> softmax = 0.1)
    if (t < RPS * DIGITS) {
        float a = 0.f;
        int r_l = t / 10, d = t - r_l * 10;
        const float* p0 = ab + (size_t)(r0 + r_l) * DIGITS + d;
        for (int bu = 0; bu < nbuf; ++bu)
#pragma unroll
            for (int yy = 0; yy < YBLK; ++yy)
                a += p0[(size_t)bu * AB_STRIDE + (size_t)yy * (R_NODES * DIGITS)];
        cs[t] = a;
    }
    __syncthreads();
    if (t < RPS) {
        float e[DIGITS];
        float m = -1e30f;
#pragma unroll
        for (int d = 0; d < DIGITS; ++d) m = fmaxf(m, cs[t*10 + d]);
        float ssum = 0.f;
#pragma unroll
        for (int d = 0; d < DIGITS; ++d) { e[d] = expf(cs[t*10 + d] - m); ssum += e[d]; }
        float inv = 1.f / ssum;
#pragma unroll
        for (int d = 0; d < DIGITS; ++d) cs[t*10 + d] = e[d] * inv;
    }
    __syncthreads();

    // ---- 3. main loop: u broadcast from LDS, W streamed global->regs (L1)
    float acc[4][10];
#pragma unroll
    for (int jj = 0; jj < 4; ++jj)
#pragma unroll
        for (int j = 0; j < 10; ++j) acc[jj][j] = 0.f;

    const float* Wb = W + (size_t)r0 * W_PER_R + (size_t)o * IN_CH;

    for (int r_l = 0; r_l < RPS; ++r_l) {
        float4 ua[4], ub2[4];
#pragma unroll
        for (int jj = 0; jj < 4; ++jj) {
            const float* up = &ut[(bs * 4 + jj) * UPAD + r_l * 8];
            ua[jj]  = *(const float4*)up;
            ub2[jj] = *(const float4*)(up + 4);
        }
        const float* Wr = Wb + (size_t)r_l * W_PER_R;
#pragma unroll
        for (int d = 0; d < 10; ++d) {
            const float4* wp = (const float4*)(Wr + d * 128);
            float4 w0 = wp[0], w1 = wp[1];
            float cv = cs[r_l * 10 + d];
#pragma unroll
            for (int jj = 0; jj < 4; ++jj) {
                float uh;
                uh = w0.x * ua[jj].x;
                uh = fmaf(w0.y, ua[jj].y, uh);
                uh = fmaf(w0.z, ua[jj].z, uh);
                uh = fmaf(w0.w, ua[jj].w, uh);
                uh = fmaf(w1.x, ub2[jj].x, uh);
                uh = fmaf(w1.y, ub2[jj].y, uh);
                uh = fmaf(w1.z, ub2[jj].z, uh);
                uh = fmaf(w1.w, ub2[jj].w, uh);
                acc[jj][d] = fmaf(uh, cv, acc[jj][d]);
            }
        }
    }

    // ---- 4. store (transposed, coalesced f4): part[split][d*16+o][b0+bs*4 ..+3]
    float* pp = part + (size_t)split * (BATCH * COLS) + b0 + bs * 4;
#pragma unroll
    for (int d = 0; d < 10; ++d) {
        *(float4*)(pp + (size_t)(d * 16 + o) * BATCH) =
            make_float4(acc[0][d], acc[1][d], acc[2][d], acc[3][d]);
    }
}

// ---------- reduce partials -> s^T ; accumulate global sum of squares ----------
// Layout-blind: linear over the 40960 elements of the [160][256] layout.
__global__ void k_sq(const float* __restrict__ part,
                     float* __restrict__ s,
                     float* __restrict__ sq)
{
    const int t = threadIdx.x;
    const int e0 = blockIdx.x * 64;
    const int el = t & 63, q = t >> 6;
    float v = 0.f;
    for (int sp = q; sp < NSPLIT; sp += 4)
        v += part[(size_t)sp * (BATCH * COLS) + e0 + el];
    __shared__ float red[256];
    red[t] = v;
    __syncthreads();
    if (t < 64) {
        float vv = red[t] + red[t + 64] + red[t + 128] + red[t + 192];
        s[e0 + t] = vv;
        float x = vv * vv;
#pragma unroll
        for (int off = 32; off > 0; off >>= 1)
            x += __shfl_down(x, off, 64);
        if (t == 0) atomicAdd(sq, x);
    }
}

// ---------- agreement partials: ab[y][r,d] = scale * sum_{b in y,o} u_hat*s ----------
// s is [col][batch] now: stage slice into column-major pad-33 LDS tile;
// inner read st_t[(tt+32k)*33 + b] = 32 distinct banks, conflict-free.
__global__ __launch_bounds__(256) void k_a(
    const float* __restrict__ u,
    const float* __restrict__ W,
    const float* __restrict__ sT,     // [160][256]
    const float* __restrict__ sq,
    float* __restrict__ ab)
{
    __shared__ float st_t[COLS * 33]; // 21.1 KB, [col][b] pad 33
    __shared__ float ut[32 * 64];     // 8 KB
    const int t = threadIdx.x;
    const int rblk = blockIdx.x;
    const int r = rblk * 8 + (t >> 5);
    const int tt = t & 31;
    const int bstart = blockIdx.y * 32;

    // stage s^T slice: 160 cols x 32 b (coalesced 128B runs per col)
#pragma unroll
    for (int p = 0; p < 5; ++p) {
        int idx = t + p * 256;            // 0..1279
        int col = idx >> 3, boff = (idx & 7) * 4;
        *(float4*)&st_t[col * 33 + boff] =
            *(const float4*)(sT + (size_t)col * BATCH + bstart + boff);
    }
#pragma unroll
    for (int p = 0; p < 2; ++p) {
        int idx = t + p * 256;
        int bb = idx >> 4, qq = idx & 15;
        ((float4*)ut)[idx] =
            ((const float4*)(u + (size_t)(bstart + bb) * (R_NODES*IN_CH) + (size_t)rblk * 64))[qq];
    }

    float wreg[5][8];
#pragma unroll
    for (int k = 0; k < 5; ++k) {
        const float4* wp = (const float4*)(W + (size_t)r * W_PER_R + (size_t)(tt + 32*k) * IN_CH);
        float4 w0 = wp[0], w1 = wp[1];
        wreg[k][0]=w0.x; wreg[k][1]=w0.y; wreg[k][2]=w0.z; wreg[k][3]=w0.w;
        wreg[k][4]=w1.x; wreg[k][5]=w1.y; wreg[k][6]=w1.z; wreg[k][7]=w1.w;
    }
    __syncthreads();

    float acc[5] = {0.f, 0.f, 0.f, 0.f, 0.f};
#pragma unroll 2
    for (int b = 0; b < 32; ++b) {
        const float* ub = &ut[b * 64 + (t >> 5) * 8];
        float4 a0 = *(const float4*)ub;
        float4 a1 = *(const float4*)(ub + 4);
#pragma unroll
        for (int k = 0; k < 5; ++k) {
            float vv = st_t[(tt + 32*k) * 33 + b];
            float uh;
            uh = wreg[k][0] * a0.x;
            uh = fmaf(wreg[k][1], a0.y, uh);
            uh = fmaf(wreg[k][2], a0.z, uh);
            uh = fmaf(wreg[k][3], a0.w, uh);
            uh = fmaf(wreg[k][4], a1.x, uh);
            uh = fmaf(wreg[k][5], a1.y, uh);
            uh = fmaf(wreg[k][6], a1.z, uh);
            uh = fmaf(wreg[k][7], a1.w, uh);
            acc[k] = fmaf(uh, vv, acc[k]);
        }
    }
    float q = *sq;
    float scale = sqrtf(q) / (1.f + q);
    float* abp = ab + (size_t)blockIdx.y * (R_NODES * DIGITS) + r * DIGITS;
#pragma unroll
    for (int k = 0; k < 5; ++k) {
        float x = acc[k] * scale;
        x += __shfl_xor(x, 1, 64);
        x += __shfl_xor(x, 2, 64);
        x += __shfl_xor(x, 4, 64);
        x += __shfl_xor(x, 8, 64);
        if ((tt & 15) == 0) {
            int d = (tt >> 4) + 2*k;
            abp[d] = x;
        }
    }
}

// ---------- final output: out[b][col] = s^T[col][b] * scale ----------
__global__ void k_scale(const float* __restrict__ sT,
                        const float* __restrict__ sq,
                        float* __restrict__ out)
{
    int e = blockIdx.x * 256 + threadIdx.x;   // linear over s^T
    float q = *sq;
    float scale = sqrtf(q) / (1.f + q);
    int col = e >> 8, b = e & 255;
    out[(size_t)b * COLS + col] = sT[e] * scale;
}

extern "C" void kernel_launch(void* const* d_in, const int* in_sizes, int n_in,
                              void* d_out, int out_size, void* d_ws, size_t ws_size,
                              hipStream_t stream)
{
    const float* u = (const float*)d_in[0];   // (256, 1152, 8)
    const float* W = (const float*)d_in[1];   // (1, 1152, 10, 16, 8)
    float* out = (float*)d_out;               // (256, 10, 16)
    float* ws = (float*)d_ws;

    float* s    = ws;                          // 40960 floats ([160][256])
    float* sq   = ws + 40960;                  // 1 (padded to 64)
    float* ab   = ws + 41024;                  // 2 * 92160
    float* part = ws + 41024 + 2 * AB_STRIDE;  // 192 * 40960 (~31.5 MB)

    for (int it = 0; it < 3; ++it) {
        k_s<<<dim3(NSPLIT, 4), dim3(256), 0, stream>>>(u, W, ab, part, sq, it);
        k_sq<<<dim3(BATCH * COLS / 64), dim3(256), 0, stream>>>(part, s, sq);
        if (it < 2)
            k_a<<<dim3(R_NODES / 8, YBLK), dim3(256), 0, stream>>>(u, W, s, sq,
                                                                   ab + (size_t)it * AB_STRIDE);
        else
            k_scale<<<dim3(BATCH * COLS / 256), dim3(256), 0, stream>>>(s, sq, out);
    }
}